// Round 10
// baseline (3400.683 us; speedup 1.0000x reference)
//
#include <hip/hip_runtime.h>

typedef _Float16 f16;
typedef _Float16 half8 __attribute__((ext_vector_type(8)));
typedef float f32x4 __attribute__((ext_vector_type(4)));
typedef char char8v __attribute__((ext_vector_type(8)));

#define N_ATOMS 100000
#define N_EDGES 200000
#define N_MOLS  4096
#define D_V 133
#define D_E 14
#define D_H 512
#define KC  672        // padded K for [W_h(512); W_i(147)] and [W_o_m(512); W_o_v(133)]

// ---- weight build: Wt[n][k] f16 transposed, from stacked f32 W1[r1][512], W2[r2][512]
__global__ void wt_build(const float* __restrict__ W1, int r1,
                         const float* __restrict__ W2, int r2,
                         f16* __restrict__ Wt) {
    int gid = blockIdx.x * blockDim.x + threadIdx.x;
    if (gid >= D_H * KC) return;
    int n = gid / KC;
    int k = gid - n * KC;
    float x = 0.f;
    if (k < r1) x = W1[k * D_H + n];
    else if (k < r1 + r2) x = W2[(k - r1) * D_H + n];
    Wt[gid] = (f16)x;
}

// ---- CSR build over edge_dst
__global__ void csr_hist(const int* __restrict__ edst, int* __restrict__ cnt) {
    int e = blockIdx.x * blockDim.x + threadIdx.x;
    if (e < N_EDGES) atomicAdd(&cnt[edst[e]], 1);
}

__global__ __launch_bounds__(1024) void csr_scan(const int* __restrict__ cnt,
                                                 int* __restrict__ off, int* __restrict__ pos) {
    __shared__ int sums[1024];
    const int tid = threadIdx.x;
    const int lo = tid * 98;
    const int hi = min(lo + 98, N_ATOMS);
    int s = 0;
    for (int i = lo; i < hi; ++i) s += cnt[i];
    sums[tid] = s;
    __syncthreads();
    for (int d = 1; d < 1024; d <<= 1) {
        int v = (tid >= d) ? sums[tid - d] : 0;
        __syncthreads();
        sums[tid] += v;
        __syncthreads();
    }
    int run = sums[tid] - s;  // exclusive base
    for (int i = lo; i < hi; ++i) { off[i] = run; pos[i] = run; run += cnt[i]; }
    if (tid == 1023) off[N_ATOMS] = run;
}

__global__ void csr_scatter(const int* __restrict__ edst, int* __restrict__ pos,
                            int* __restrict__ eid) {
    int e = blockIdx.x * blockDim.x + threadIdx.x;
    if (e < N_EDGES) {
        int idx = atomicAdd(&pos[edst[e]], 1);
        eid[idx] = e;
    }
}

// ---- node message sum via CSR gather -> block-scaled int8
__global__ __launch_bounds__(512) void seg_csr(
    const f16* __restrict__ H, const int* __restrict__ off, const int* __restrict__ eid,
    unsigned int* __restrict__ MnQ32, float* __restrict__ Msc)
{
    const int n = blockIdx.x * 8 + (threadIdx.x >> 6);
    const int lane = threadIdx.x & 63;
    const int j0 = off[n], j1 = off[n + 1];
    float acc[8];
    #pragma unroll
    for (int k = 0; k < 8; ++k) acc[k] = 0.f;
    for (int j = j0; j < j1; ++j) {
        const int e = eid[j];
        const half8 h = *reinterpret_cast<const half8*>(&H[e * D_H + lane * 8]);
        #pragma unroll
        for (int k = 0; k < 8; ++k) acc[k] += (float)h[k];
    }
    float m = 0.f;
    #pragma unroll
    for (int k = 0; k < 8; ++k) m = fmaxf(m, fabsf(acc[k]));
    m = fmaxf(m, __shfl_xor(m, 1));
    m = fmaxf(m, __shfl_xor(m, 2));
    m = fmaxf(m, 1e-20f);
    const float s = m * (1.f / 127.f);
    const float inv_s = 127.f / m;
    if ((lane & 3) == 0) Msc[n * 16 + (lane >> 2)] = s;
    int q[8];
    #pragma unroll
    for (int k = 0; k < 8; ++k) q[k] = __float2int_rn(acc[k] * inv_s);
    uint2 o;
    o.x = (q[0] & 0xff) | ((q[1] & 0xff) << 8) | ((q[2] & 0xff) << 16) | ((unsigned)(q[3] & 0xff) << 24);
    o.y = (q[4] & 0xff) | ((q[5] & 0xff) << 8) | ((q[6] & 0xff) << 16) | ((unsigned)(q[7] & 0xff) << 24);
    *reinterpret_cast<uint2*>(&MnQ32[n * 128 + lane * 2]) = o;
}

// ---- fused message-passing GEMM (in-place on Ha): NO LDS, direct MFMA-layout A loads.
//   Ha[e] = relu( [deq(Mn)[src]-Ha[rev] (512) ; V[src] (133) ; E[e] (14)] @ Wt )
// full=0 -> init pass (M tiles skipped)
__global__ __launch_bounds__(512) void gemm_pass(
    const float* __restrict__ V, const float* __restrict__ E,
    const int* __restrict__ esrc, const char* __restrict__ MnQ,
    const float* __restrict__ Msc,
    f16* __restrict__ Ha, const f16* __restrict__ Wt, int full)
{
    const int tid = threadIdx.x;
    const int lane = tid & 63;
    const int quad = lane >> 4;
    const int m16  = lane & 15;
    const int colbase = (tid >> 6) << 6;   // 8 waves x 64 cols
    const int rowblk = blockIdx.x << 6;

    int e4[4], sv4[4];
    #pragma unroll
    for (int rt = 0; rt < 4; ++rt) {
        e4[rt] = rowblk + rt * 16 + m16;
        sv4[rt] = esrc[e4[rt]];
    }

    f32x4 acc[4][4];
    #pragma unroll
    for (int a = 0; a < 4; ++a)
    #pragma unroll
    for (int b = 0; b < 4; ++b)
    #pragma unroll
    for (int r = 0; r < 4; ++r) acc[a][b][r] = 0.f;

    if (full) {
        for (int ks = 0; ks < 16; ++ks) {   // M region: 16 x 32-col tiles
            const int k0 = ks << 5;
            half8 af[4];
            #pragma unroll
            for (int rt = 0; rt < 4; ++rt) {
                const char8v q = *reinterpret_cast<const char8v*>(&MnQ[sv4[rt] * D_H + k0 + quad * 8]);
                const float  s = Msc[sv4[rt] * 16 + ks];
                const half8  h = *reinterpret_cast<const half8*>(&Ha[(e4[rt] ^ 1) * D_H + k0 + quad * 8]);
                #pragma unroll
                for (int j = 0; j < 8; ++j)
                    af[rt][j] = (f16)((float)q[j] * s - (float)h[j]);
            }
            #pragma unroll
            for (int ct = 0; ct < 4; ++ct) {
                const half8 bf = *reinterpret_cast<const half8*>(&Wt[(colbase + ct * 16 + m16) * KC + k0 + quad * 8]);
                #pragma unroll
                for (int rt = 0; rt < 4; ++rt)
                    acc[rt][ct] = __builtin_amdgcn_mfma_f32_16x16x32_f16(af[rt], bf, acc[rt][ct], 0, 0, 0);
            }
        }
    }
    for (int ks = 16; ks < 21; ++ks) {      // [V ; E ; pad] tail
        const int k0 = ks << 5;
        half8 af[4];
        #pragma unroll
        for (int rt = 0; rt < 4; ++rt) {
            #pragma unroll
            for (int j = 0; j < 8; ++j) {
                const int kk = k0 + quad * 8 + j - D_H;
                float x = 0.f;
                if (kk < D_V) x = V[sv4[rt] * D_V + kk];
                else if (kk < D_V + D_E) x = E[e4[rt] * D_E + (kk - D_V)];
                af[rt][j] = (f16)x;
            }
        }
        #pragma unroll
        for (int ct = 0; ct < 4; ++ct) {
            const half8 bf = *reinterpret_cast<const half8*>(&Wt[(colbase + ct * 16 + m16) * KC + k0 + quad * 8]);
            #pragma unroll
            for (int rt = 0; rt < 4; ++rt)
                acc[rt][ct] = __builtin_amdgcn_mfma_f32_16x16x32_f16(af[rt], bf, acc[rt][ct], 0, 0, 0);
        }
    }

    __syncthreads();   // all in-block Ha[rev] reads complete before in-place writes
    #pragma unroll
    for (int rt = 0; rt < 4; ++rt)
    #pragma unroll
    for (int ct = 0; ct < 4; ++ct)
    #pragma unroll
    for (int r = 0; r < 4; ++r) {
        const int row = rowblk + rt * 16 + quad * 4 + r;
        const int col = colbase + ct * 16 + m16;
        Ha[row * D_H + col] = (f16)fmaxf(acc[rt][ct][r], 0.f);
    }
}

// ---- output GEMM (direct loads, no LDS): Hv[a] = relu([deq(Mn)(512); V(133)] @ WtO + b_o)
__global__ __launch_bounds__(512) void gemm_out(
    const float* __restrict__ V, const char* __restrict__ MnQ,
    const float* __restrict__ Msc, const float* __restrict__ bo,
    const f16* __restrict__ Wt, f16* __restrict__ Hv)
{
    const int tid = threadIdx.x;
    const int lane = tid & 63;
    const int quad = lane >> 4;
    const int m16  = lane & 15;
    const int colbase = (tid >> 6) << 6;
    const int rowblk = blockIdx.x << 6;

    int a4[4];
    #pragma unroll
    for (int rt = 0; rt < 4; ++rt)
        a4[rt] = min(rowblk + rt * 16 + m16, N_ATOMS - 1);

    f32x4 acc[4][4];
    #pragma unroll
    for (int a = 0; a < 4; ++a)
    #pragma unroll
    for (int b = 0; b < 4; ++b)
    #pragma unroll
    for (int r = 0; r < 4; ++r) acc[a][b][r] = 0.f;

    for (int ks = 0; ks < 16; ++ks) {
        const int k0 = ks << 5;
        half8 af[4];
        #pragma unroll
        for (int rt = 0; rt < 4; ++rt) {
            const char8v q = *reinterpret_cast<const char8v*>(&MnQ[a4[rt] * D_H + k0 + quad * 8]);
            const float  s = Msc[a4[rt] * 16 + ks];
            #pragma unroll
            for (int j = 0; j < 8; ++j)
                af[rt][j] = (f16)((float)q[j] * s);
        }
        #pragma unroll
        for (int ct = 0; ct < 4; ++ct) {
            const half8 bf = *reinterpret_cast<const half8*>(&Wt[(colbase + ct * 16 + m16) * KC + k0 + quad * 8]);
            #pragma unroll
            for (int rt = 0; rt < 4; ++rt)
                acc[rt][ct] = __builtin_amdgcn_mfma_f32_16x16x32_f16(af[rt], bf, acc[rt][ct], 0, 0, 0);
        }
    }
    for (int ks = 16; ks < 21; ++ks) {
        const int k0 = ks << 5;
        half8 af[4];
        #pragma unroll
        for (int rt = 0; rt < 4; ++rt) {
            #pragma unroll
            for (int j = 0; j < 8; ++j) {
                const int kk = k0 + quad * 8 + j - D_H;
                af[rt][j] = (kk < D_V) ? (f16)V[a4[rt] * D_V + kk] : (f16)0.f;
            }
        }
        #pragma unroll
        for (int ct = 0; ct < 4; ++ct) {
            const half8 bf = *reinterpret_cast<const half8*>(&Wt[(colbase + ct * 16 + m16) * KC + k0 + quad * 8]);
            #pragma unroll
            for (int rt = 0; rt < 4; ++rt)
                acc[rt][ct] = __builtin_amdgcn_mfma_f32_16x16x32_f16(af[rt], bf, acc[rt][ct], 0, 0, 0);
        }
    }

    // no barrier needed: Hv aliases Ha but this kernel never reads Ha
    #pragma unroll
    for (int rt = 0; rt < 4; ++rt)
    #pragma unroll
    for (int ct = 0; ct < 4; ++ct)
    #pragma unroll
    for (int r = 0; r < 4; ++r) {
        const int row = rowblk + rt * 16 + quad * 4 + r;
        if (row < N_ATOMS) {
            const int col = colbase + ct * 16 + m16;
            Hv[row * D_H + col] = (f16)fmaxf(acc[rt][ct][r] + bo[col], 0.f);
        }
    }
}

// ---- molecule mean: batch sorted -> contiguous atom range per mol (binary search)
__global__ __launch_bounds__(512) void mol_mean(
    const f16* __restrict__ Hv, const int* __restrict__ batch, float* __restrict__ mean)
{
    const int m = blockIdx.x;
    __shared__ int sh[2];
    if (threadIdx.x == 0) {
        int lo = 0, hi = N_ATOMS;
        while (lo < hi) { int mid = (lo + hi) >> 1; if (batch[mid] < m) lo = mid + 1; else hi = mid; }
        sh[0] = lo;
        int lo2 = lo; hi = N_ATOMS;
        while (lo2 < hi) { int mid = (lo2 + hi) >> 1; if (batch[mid] < m + 1) lo2 = mid + 1; else hi = mid; }
        sh[1] = lo2;
    }
    __syncthreads();
    const int a0 = sh[0], a1 = sh[1];
    float acc = 0.f;
    for (int a = a0; a < a1; ++a) acc += (float)Hv[(size_t)a * D_H + threadIdx.x];
    mean[m * D_H + threadIdx.x] = acc / (float)max(a1 - a0, 1);
}

__global__ __launch_bounds__(256) void bn_stats(
    const float* __restrict__ mean_in, const float* __restrict__ gamma,
    const float* __restrict__ beta, float* __restrict__ An, float* __restrict__ Bn)
{
    const int n = blockIdx.x;
    const int tid = threadIdx.x;
    float s = 0.f, s2 = 0.f;
    for (int m = tid; m < N_MOLS; m += 256) {
        float h = mean_in[m * D_H + n];
        s += h; s2 += h * h;
    }
    for (int off = 32; off > 0; off >>= 1) {
        s  += __shfl_down(s, off);
        s2 += __shfl_down(s2, off);
    }
    __shared__ float sh[8];
    const int wave = tid >> 6, lane = tid & 63;
    if (lane == 0) { sh[wave] = s; sh[4 + wave] = s2; }
    __syncthreads();
    if (tid == 0) {
        float S  = sh[0] + sh[1] + sh[2] + sh[3];
        float S2 = sh[4] + sh[5] + sh[6] + sh[7];
        float mu = S / (float)N_MOLS;
        float var = fmaxf(S2 / (float)N_MOLS - mu * mu, 0.f);
        float sc = rsqrtf(var + 1e-5f) * gamma[n];
        An[n] = sc;
        Bn[n] = beta[n] - mu * sc;
    }
}

__global__ void bn_apply(const float* __restrict__ mean_in,
                         const float* __restrict__ An, const float* __restrict__ Bn,
                         float* __restrict__ out)
{
    int gid = blockIdx.x * blockDim.x + threadIdx.x;
    int n = gid & 511;
    out[gid] = mean_in[gid] * An[n] + Bn[n];
}

extern "C" void kernel_launch(void* const* d_in, const int* in_sizes, int n_in,
                              void* d_out, int out_size, void* d_ws, size_t ws_size,
                              hipStream_t stream)
{
    (void)in_sizes; (void)n_in; (void)out_size; (void)ws_size;
    const float* V     = (const float*)d_in[0];
    const float* E     = (const float*)d_in[1];
    const int*   esrc  = (const int*)d_in[2];
    const int*   edst  = (const int*)d_in[3];
    const int*   batch = (const int*)d_in[4];
    const float* Wi    = (const float*)d_in[5];
    const float* Wh    = (const float*)d_in[6];
    const float* Wo    = (const float*)d_in[7];
    const float* bo    = (const float*)d_in[8];
    const float* gam   = (const float*)d_in[9];
    const float* bet   = (const float*)d_in[10];
    float* out = (float*)d_out;

    // workspace layout — total 265,396,864 B (~253.1 MiB, under the 256 MiB limit)
    char* ws = (char*)d_ws;
    f16*   WtC  = (f16*)(ws + 0);                   //    688,128 B
    f16*   WtO  = (f16*)(ws + 688128);              //    688,128 B
    int*   off  = (int*)(ws + 1376256);             //    400,128 B (N_ATOMS+1 ints)
    int*   eid  = (int*)(ws + 1776384);             //    800,000 B
    int*   cnt  = (int*)(ws + 2576384);             //    400,000 B (also 'pos' cursor)
    float* An   = (float*)(ws + 2992768);           //      2,048 B
    float* Bn   = (float*)(ws + 2994816);           //      2,048 B
    f16*   Ha   = (f16*)(ws + 2996864);             // 204,800,000 B (edge states; reused as Hv)
    char*  MnQ  = (char*)(ws + 207796864);          //  51,200,000 B int8
    float* Msc  = (float*)(ws + 258996864);         //   6,400,000 B scales
    unsigned int* MnQ32 = (unsigned int*)MnQ;
    f16*   Hv   = Ha;                                // Ha is dead after final seg_csr
    float* mean = out;                               // mol means live in d_out

    // weights
    wt_build<<<(D_H * KC + 255) / 256, 256, 0, stream>>>(Wh, D_H, Wi, D_V + D_E, WtC);
    wt_build<<<(D_H * KC + 255) / 256, 256, 0, stream>>>(Wo + D_V * D_H, D_H, Wo, D_V, WtO);

    // CSR over edge_dst (cnt doubles as scatter cursor 'pos')
    hipMemsetAsync(cnt, 0, 400000, stream);
    csr_hist<<<(N_EDGES + 511) / 512, 512, 0, stream>>>(edst, cnt);
    csr_scan<<<1, 1024, 0, stream>>>(cnt, off, cnt);
    csr_scatter<<<(N_EDGES + 511) / 512, 512, 0, stream>>>(edst, cnt, eid);

    // init: H = relu([V;E] @ W_i)   (M tiles skipped: full=0)
    gemm_pass<<<N_EDGES / 64, 512, 0, stream>>>(V, E, esrc, MnQ, Msc, Ha, WtC, 0);

    // DEPTH-1 = 2 message-passing iterations (int8 block-scaled Mn)
    for (int it = 0; it < 2; ++it) {
        seg_csr<<<N_ATOMS / 8, 512, 0, stream>>>(Ha, off, eid, MnQ32, Msc);
        gemm_pass<<<N_EDGES / 64, 512, 0, stream>>>(V, E, esrc, MnQ, Msc, Ha, WtC, 1);
    }

    // final edge->node aggregation
    seg_csr<<<N_ATOMS / 8, 512, 0, stream>>>(Ha, off, eid, MnQ32, Msc);

    // output GEMM -> Hv (reuses Ha), then mol means + BatchNorm
    gemm_out<<<(N_ATOMS + 63) / 64, 512, 0, stream>>>(V, MnQ, Msc, bo, WtO, Hv);
    mol_mean<<<N_MOLS, 512, 0, stream>>>(Hv, batch, mean);
    bn_stats<<<D_H, 256, 0, stream>>>(mean, gam, bet, An, Bn);
    bn_apply<<<(N_MOLS * D_H) / 256, 256, 0, stream>>>(mean, An, Bn, out);
}

// Round 11
// 1515.545 us; speedup vs baseline: 2.2439x; 2.2439x over previous
//
#include <hip/hip_runtime.h>

typedef _Float16 f16;
typedef _Float16 half8 __attribute__((ext_vector_type(8)));
typedef _Float16 half4v __attribute__((ext_vector_type(4)));
typedef float f32x4 __attribute__((ext_vector_type(4)));

#define N_ATOMS 100000
#define N_EDGES 200000
#define N_MOLS  4096
#define D_V 133
#define D_E 14
#define D_H 512
#define KC  672        // padded K for [W_h(512); W_i(147)] and [W_o_m(512); W_o_v(133)]
#define KSE 21         // 32-wide K tiles
#define LDA 40         // LDS A-tile row stride (f16 elems): 80 B rows

// ---- weight build, swizzled to MFMA fragment order:
//   B_swz[(((n>>4)*21 + (k>>5))*64 + ((k>>3)&3)*16 + (n&15))*8 + (k&7)] = W[k][n]
//   -> per (col-tile, k-tile) a wave's 64 lanes read one contiguous 1KB block.
__global__ void wt_build_swz(const float* __restrict__ W1, int r1,
                             const float* __restrict__ W2, int r2,
                             f16* __restrict__ WtS) {
    int gid = blockIdx.x * blockDim.x + threadIdx.x;
    if (gid >= D_H * KC) return;
    int n = gid / KC;
    int k = gid - n * KC;
    float x = 0.f;
    if (k < r1) x = W1[k * D_H + n];
    else if (k < r1 + r2) x = W2[(k - r1) * D_H + n];
    const int dst = ((((n >> 4) * KSE + (k >> 5)) << 6) + (((k >> 3) & 3) << 4) + (n & 15)) * 8 + (k & 7);
    WtS[dst] = (f16)x;
}

// ---- CSR build over edge_dst
__global__ void csr_hist(const int* __restrict__ edst, int* __restrict__ cnt) {
    int e = blockIdx.x * blockDim.x + threadIdx.x;
    if (e < N_EDGES) atomicAdd(&cnt[edst[e]], 1);
}

__global__ __launch_bounds__(1024) void csr_scan(const int* __restrict__ cnt,
                                                 int* __restrict__ off, int* __restrict__ pos) {
    __shared__ int sums[1024];
    const int tid = threadIdx.x;
    const int lo = tid * 98;
    const int hi = min(lo + 98, N_ATOMS);
    int s = 0;
    for (int i = lo; i < hi; ++i) s += cnt[i];
    sums[tid] = s;
    __syncthreads();
    for (int d = 1; d < 1024; d <<= 1) {
        int v = (tid >= d) ? sums[tid - d] : 0;
        __syncthreads();
        sums[tid] += v;
        __syncthreads();
    }
    int run = sums[tid] - s;  // exclusive base
    for (int i = lo; i < hi; ++i) { off[i] = run; pos[i] = run; run += cnt[i]; }
    if (tid == 1023) off[N_ATOMS] = run;
}

__global__ void csr_scatter(const int* __restrict__ edst, int* __restrict__ pos,
                            int* __restrict__ eid) {
    int e = blockIdx.x * blockDim.x + threadIdx.x;
    if (e < N_EDGES) {
        int idx = atomicAdd(&pos[edst[e]], 1);
        eid[idx] = e;
    }
}

// ---- node message sum via CSR gather -> block-scaled int8
__global__ __launch_bounds__(512) void seg_csr(
    const f16* __restrict__ H, const int* __restrict__ off, const int* __restrict__ eid,
    unsigned int* __restrict__ MnQ32, float* __restrict__ Msc)
{
    const int n = blockIdx.x * 8 + (threadIdx.x >> 6);
    const int lane = threadIdx.x & 63;
    const int j0 = off[n], j1 = off[n + 1];
    float acc[8];
    #pragma unroll
    for (int k = 0; k < 8; ++k) acc[k] = 0.f;
    for (int j = j0; j < j1; ++j) {
        const int e = eid[j];
        const half8 h = *reinterpret_cast<const half8*>(&H[e * D_H + lane * 8]);
        #pragma unroll
        for (int k = 0; k < 8; ++k) acc[k] += (float)h[k];
    }
    float m = 0.f;
    #pragma unroll
    for (int k = 0; k < 8; ++k) m = fmaxf(m, fabsf(acc[k]));
    m = fmaxf(m, __shfl_xor(m, 1));
    m = fmaxf(m, __shfl_xor(m, 2));
    m = fmaxf(m, 1e-20f);
    const float s = m * (1.f / 127.f);
    const float inv_s = 127.f / m;
    if ((lane & 3) == 0) Msc[n * 16 + (lane >> 2)] = s;
    int q[8];
    #pragma unroll
    for (int k = 0; k < 8; ++k) q[k] = __float2int_rn(acc[k] * inv_s);
    uint2 o;
    o.x = (q[0] & 0xff) | ((q[1] & 0xff) << 8) | ((q[2] & 0xff) << 16) | ((unsigned)(q[3] & 0xff) << 24);
    o.y = (q[4] & 0xff) | ((q[5] & 0xff) << 8) | ((q[6] & 0xff) << 16) | ((unsigned)(q[7] & 0xff) << 24);
    *reinterpret_cast<uint2*>(&MnQ32[n * 128 + lane * 2]) = o;
}

// ---- fused message-passing GEMM (in-place on Ha), BK=32, 1-deep prefetch, swizzled B
__global__ __launch_bounds__(512) void gemm_pass(
    const float* __restrict__ V, const float* __restrict__ E,
    const int* __restrict__ esrc, const char* __restrict__ MnQ,
    const float* __restrict__ Msc,
    f16* __restrict__ Ha, const f16* __restrict__ WtS, int ks_begin)
{
    __shared__ __align__(16) f16 Al[64 * LDA];
    const int tid = threadIdx.x;
    const int rowblk = blockIdx.x << 6;
    const int srow = tid >> 3;
    const int skk  = (tid & 7) << 2;
    const int e_s  = rowblk + srow;
    const int sv   = esrc[e_s];
    const int rev  = e_s ^ 1;
    const int lane = tid & 63;
    const int quad = lane >> 4;
    const int m16  = lane & 15;
    const int colbase = (tid >> 6) << 6;
    const int cb0 = (tid >> 6) << 2;          // first of this wave's 4 col-tiles
    const f16* WtL = WtS + lane * 8;          // lane-constant fragment base

    f32x4 acc[4][4];
    #pragma unroll
    for (int a = 0; a < 4; ++a)
    #pragma unroll
    for (int b = 0; b < 4; ++b)
    #pragma unroll
    for (int r = 0; r < 4; ++r) acc[a][b][r] = 0.f;

    // prefetch registers
    char4 pq; float ps; half4v ph; float pv[4];
    auto issue = [&](int ks) {
        const int k0 = ks << 5;
        if (k0 < D_H) {
            pq = *reinterpret_cast<const char4*>(&MnQ[sv * D_H + k0 + skk]);
            ps = Msc[sv * 16 + (k0 >> 5)];
            ph = *reinterpret_cast<const half4v*>(&Ha[rev * D_H + k0 + skk]);
        } else {
            #pragma unroll
            for (int j = 0; j < 4; ++j) {
                const int kk = k0 + skk + j - D_H;
                float x = 0.f;
                if (kk < D_V) x = V[sv * D_V + kk];
                else if (kk < D_V + D_E) x = E[e_s * D_E + (kk - D_V)];
                pv[j] = x;
            }
        }
    };

    issue(ks_begin);
    for (int ks = ks_begin; ks < KSE; ++ks) {
        const int k0 = ks << 5;
        half4v w;
        if (k0 < D_H) {
            w[0] = (f16)((float)pq.x * ps - (float)ph[0]);
            w[1] = (f16)((float)pq.y * ps - (float)ph[1]);
            w[2] = (f16)((float)pq.z * ps - (float)ph[2]);
            w[3] = (f16)((float)pq.w * ps - (float)ph[3]);
        } else {
            w[0] = (f16)pv[0]; w[1] = (f16)pv[1]; w[2] = (f16)pv[2]; w[3] = (f16)pv[3];
        }
        __syncthreads();
        *reinterpret_cast<half4v*>(&Al[srow * LDA + skk]) = w;
        __syncthreads();
        if (ks + 1 < KSE) issue(ks + 1);  // overlap with MFMA below
        half8 af[4];
        #pragma unroll
        for (int rt = 0; rt < 4; ++rt)
            af[rt] = *reinterpret_cast<const half8*>(&Al[(rt * 16 + m16) * LDA + quad * 8]);
        #pragma unroll
        for (int ct = 0; ct < 4; ++ct) {
            const half8 bf = *reinterpret_cast<const half8*>(&WtL[(((cb0 + ct) * KSE + ks) << 9)]);
            #pragma unroll
            for (int rt = 0; rt < 4; ++rt)
                acc[rt][ct] = __builtin_amdgcn_mfma_f32_16x16x32_f16(af[rt], bf, acc[rt][ct], 0, 0, 0);
        }
    }

    // epilogue: in-place overwrite is safe (all Ha[rev] reads are in-block, barrier-ordered)
    #pragma unroll
    for (int rt = 0; rt < 4; ++rt)
    #pragma unroll
    for (int ct = 0; ct < 4; ++ct)
    #pragma unroll
    for (int r = 0; r < 4; ++r) {
        const int row = rowblk + rt * 16 + quad * 4 + r;
        const int col = colbase + ct * 16 + m16;
        Ha[row * D_H + col] = (f16)fmaxf(acc[rt][ct][r], 0.f);
    }
}

// ---- output GEMM: Hv[a] = relu([deq(Mn)(512); V(133)] @ WtO + b_o), swizzled B
__global__ __launch_bounds__(512) void gemm_out(
    const float* __restrict__ V, const char* __restrict__ MnQ,
    const float* __restrict__ Msc, const float* __restrict__ bo,
    const f16* __restrict__ WtS, f16* __restrict__ Hv)
{
    __shared__ __align__(16) f16 Al[64 * LDA];
    __shared__ float bo_s[D_H];
    const int tid = threadIdx.x;
    const int rowblk = blockIdx.x << 6;
    bo_s[tid] = bo[tid];
    const int srow = tid >> 3;
    const int skk  = (tid & 7) << 2;
    const int arow = min(rowblk + srow, N_ATOMS - 1);
    const int lane = tid & 63;
    const int quad = lane >> 4;
    const int m16  = lane & 15;
    const int colbase = (tid >> 6) << 6;
    const int cb0 = (tid >> 6) << 2;
    const f16* WtL = WtS + lane * 8;

    f32x4 acc[4][4];
    #pragma unroll
    for (int a = 0; a < 4; ++a)
    #pragma unroll
    for (int b = 0; b < 4; ++b)
    #pragma unroll
    for (int r = 0; r < 4; ++r) acc[a][b][r] = 0.f;

    char4 pq; float ps; float pv[4];
    auto issue = [&](int ks) {
        const int k0 = ks << 5;
        if (k0 < D_H) {
            pq = *reinterpret_cast<const char4*>(&MnQ[arow * D_H + k0 + skk]);
            ps = Msc[arow * 16 + (k0 >> 5)];
        } else {
            #pragma unroll
            for (int j = 0; j < 4; ++j) {
                const int kk = k0 + skk + j - D_H;
                pv[j] = (kk < D_V) ? V[arow * D_V + kk] : 0.f;
            }
        }
    };

    issue(0);
    for (int ks = 0; ks < KSE; ++ks) {
        const int k0 = ks << 5;
        half4v w;
        if (k0 < D_H) {
            w[0] = (f16)((float)pq.x * ps);
            w[1] = (f16)((float)pq.y * ps);
            w[2] = (f16)((float)pq.z * ps);
            w[3] = (f16)((float)pq.w * ps);
        } else {
            w[0] = (f16)pv[0]; w[1] = (f16)pv[1]; w[2] = (f16)pv[2]; w[3] = (f16)pv[3];
        }
        __syncthreads();
        *reinterpret_cast<half4v*>(&Al[srow * LDA + skk]) = w;
        __syncthreads();
        if (ks + 1 < KSE) issue(ks + 1);
        half8 af[4];
        #pragma unroll
        for (int rt = 0; rt < 4; ++rt)
            af[rt] = *reinterpret_cast<const half8*>(&Al[(rt * 16 + m16) * LDA + quad * 8]);
        #pragma unroll
        for (int ct = 0; ct < 4; ++ct) {
            const half8 bf = *reinterpret_cast<const half8*>(&WtL[(((cb0 + ct) * KSE + ks) << 9)]);
            #pragma unroll
            for (int rt = 0; rt < 4; ++rt)
                acc[rt][ct] = __builtin_amdgcn_mfma_f32_16x16x32_f16(af[rt], bf, acc[rt][ct], 0, 0, 0);
        }
    }

    #pragma unroll
    for (int rt = 0; rt < 4; ++rt)
    #pragma unroll
    for (int ct = 0; ct < 4; ++ct)
    #pragma unroll
    for (int r = 0; r < 4; ++r) {
        const int row = rowblk + rt * 16 + quad * 4 + r;
        if (row < N_ATOMS) {
            const int col = colbase + ct * 16 + m16;
            Hv[row * D_H + col] = (f16)fmaxf(acc[rt][ct][r] + bo_s[col], 0.f);
        }
    }
}

// ---- molecule mean: batch sorted -> contiguous atom range per mol (binary search)
__global__ __launch_bounds__(512) void mol_mean(
    const f16* __restrict__ Hv, const int* __restrict__ batch, float* __restrict__ mean)
{
    const int m = blockIdx.x;
    __shared__ int sh[2];
    if (threadIdx.x == 0) {
        int lo = 0, hi = N_ATOMS;
        while (lo < hi) { int mid = (lo + hi) >> 1; if (batch[mid] < m) lo = mid + 1; else hi = mid; }
        sh[0] = lo;
        int lo2 = lo; hi = N_ATOMS;
        while (lo2 < hi) { int mid = (lo2 + hi) >> 1; if (batch[mid] < m + 1) lo2 = mid + 1; else hi = mid; }
        sh[1] = lo2;
    }
    __syncthreads();
    const int a0 = sh[0], a1 = sh[1];
    float acc = 0.f;
    for (int a = a0; a < a1; ++a) acc += (float)Hv[(size_t)a * D_H + threadIdx.x];
    mean[m * D_H + threadIdx.x] = acc / (float)max(a1 - a0, 1);
}

__global__ __launch_bounds__(256) void bn_stats(
    const float* __restrict__ mean_in, const float* __restrict__ gamma,
    const float* __restrict__ beta, float* __restrict__ An, float* __restrict__ Bn)
{
    const int n = blockIdx.x;
    const int tid = threadIdx.x;
    float s = 0.f, s2 = 0.f;
    for (int m = tid; m < N_MOLS; m += 256) {
        float h = mean_in[m * D_H + n];
        s += h; s2 += h * h;
    }
    for (int off = 32; off > 0; off >>= 1) {
        s  += __shfl_down(s, off);
        s2 += __shfl_down(s2, off);
    }
    __shared__ float sh[8];
    const int wave = tid >> 6, lane = tid & 63;
    if (lane == 0) { sh[wave] = s; sh[4 + wave] = s2; }
    __syncthreads();
    if (tid == 0) {
        float S  = sh[0] + sh[1] + sh[2] + sh[3];
        float S2 = sh[4] + sh[5] + sh[6] + sh[7];
        float mu = S / (float)N_MOLS;
        float var = fmaxf(S2 / (float)N_MOLS - mu * mu, 0.f);
        float sc = rsqrtf(var + 1e-5f) * gamma[n];
        An[n] = sc;
        Bn[n] = beta[n] - mu * sc;
    }
}

__global__ void bn_apply(const float* __restrict__ mean_in,
                         const float* __restrict__ An, const float* __restrict__ Bn,
                         float* __restrict__ out)
{
    int gid = blockIdx.x * blockDim.x + threadIdx.x;
    int n = gid & 511;
    out[gid] = mean_in[gid] * An[n] + Bn[n];
}

extern "C" void kernel_launch(void* const* d_in, const int* in_sizes, int n_in,
                              void* d_out, int out_size, void* d_ws, size_t ws_size,
                              hipStream_t stream)
{
    (void)in_sizes; (void)n_in; (void)out_size; (void)ws_size;
    const float* V     = (const float*)d_in[0];
    const float* E     = (const float*)d_in[1];
    const int*   esrc  = (const int*)d_in[2];
    const int*   edst  = (const int*)d_in[3];
    const int*   batch = (const int*)d_in[4];
    const float* Wi    = (const float*)d_in[5];
    const float* Wh    = (const float*)d_in[6];
    const float* Wo    = (const float*)d_in[7];
    const float* bo    = (const float*)d_in[8];
    const float* gam   = (const float*)d_in[9];
    const float* bet   = (const float*)d_in[10];
    float* out = (float*)d_out;

    // workspace layout — total 265,396,864 B (~253.1 MiB, under the 256 MiB limit)
    char* ws = (char*)d_ws;
    f16*   WtC  = (f16*)(ws + 0);                   //    688,128 B (swizzled)
    f16*   WtO  = (f16*)(ws + 688128);              //    688,128 B (swizzled)
    int*   off  = (int*)(ws + 1376256);             //    400,128 B (N_ATOMS+1 ints)
    int*   eid  = (int*)(ws + 1776384);             //    800,000 B
    int*   cnt  = (int*)(ws + 2576384);             //    400,000 B (also 'pos' cursor)
    float* An   = (float*)(ws + 2992768);           //      2,048 B
    float* Bn   = (float*)(ws + 2994816);           //      2,048 B
    f16*   Ha   = (f16*)(ws + 2996864);             // 204,800,000 B (edge states; reused as Hv)
    char*  MnQ  = (char*)(ws + 207796864);          //  51,200,000 B int8
    float* Msc  = (float*)(ws + 258996864);         //   6,400,000 B scales
    unsigned int* MnQ32 = (unsigned int*)MnQ;
    f16*   Hv   = Ha;                                // Ha is dead after final seg_csr
    float* mean = out;                               // mol means live in d_out

    // weights (swizzled to MFMA fragment order)
    wt_build_swz<<<(D_H * KC + 255) / 256, 256, 0, stream>>>(Wh, D_H, Wi, D_V + D_E, WtC);
    wt_build_swz<<<(D_H * KC + 255) / 256, 256, 0, stream>>>(Wo + D_V * D_H, D_H, Wo, D_V, WtO);

    // CSR over edge_dst (cnt doubles as scatter cursor 'pos')
    hipMemsetAsync(cnt, 0, 400000, stream);
    csr_hist<<<(N_EDGES + 511) / 512, 512, 0, stream>>>(edst, cnt);
    csr_scan<<<1, 1024, 0, stream>>>(cnt, off, cnt);
    csr_scatter<<<(N_EDGES + 511) / 512, 512, 0, stream>>>(edst, cnt, eid);

    // init: H = relu([V;E] @ W_i)   (M tiles skipped: ks_begin=16)
    gemm_pass<<<N_EDGES / 64, 512, 0, stream>>>(V, E, esrc, MnQ, Msc, Ha, WtC, 16);

    // DEPTH-1 = 2 message-passing iterations (int8 block-scaled Mn)
    for (int it = 0; it < 2; ++it) {
        seg_csr<<<N_ATOMS / 8, 512, 0, stream>>>(Ha, off, eid, MnQ32, Msc);
        gemm_pass<<<N_EDGES / 64, 512, 0, stream>>>(V, E, esrc, MnQ, Msc, Ha, WtC, 0);
    }

    // final edge->node aggregation
    seg_csr<<<N_ATOMS / 8, 512, 0, stream>>>(Ha, off, eid, MnQ32, Msc);

    // output GEMM -> Hv (reuses Ha), then mol means + BatchNorm
    gemm_out<<<(N_ATOMS + 63) / 64, 512, 0, stream>>>(V, MnQ, Msc, bo, WtO, Hv);
    mol_mean<<<N_MOLS, 512, 0, stream>>>(Hv, batch, mean);
    bn_stats<<<D_H, 256, 0, stream>>>(mean, gam, bet, An, Bn);
    bn_apply<<<(N_MOLS * D_H) / 256, 256, 0, stream>>>(mean, An, Bn, out);
}

// Round 12
// 1510.322 us; speedup vs baseline: 2.2516x; 1.0035x over previous
//
#include <hip/hip_runtime.h>

typedef _Float16 f16;
typedef _Float16 half8 __attribute__((ext_vector_type(8)));
typedef _Float16 half4v __attribute__((ext_vector_type(4)));
typedef float f32x4 __attribute__((ext_vector_type(4)));

#define N_ATOMS 100000
#define N_EDGES 200000
#define N_MOLS  4096
#define D_V 133
#define D_E 14
#define D_H 512
#define KC  672        // padded K for [W_h(512); W_i(147)] and [W_o_m(512); W_o_v(133)]
#define KSE 21         // 32-wide K tiles
#define LDA 40         // LDS A-tile row stride (f16 elems): 80 B rows

// ---- weight build, swizzled to MFMA fragment order:
//   B_swz[(((n>>4)*21 + (k>>5))*64 + ((k>>3)&3)*16 + (n&15))*8 + (k&7)] = W[k][n]
__global__ void wt_build_swz(const float* __restrict__ W1, int r1,
                             const float* __restrict__ W2, int r2,
                             f16* __restrict__ WtS) {
    int gid = blockIdx.x * blockDim.x + threadIdx.x;
    if (gid >= D_H * KC) return;
    int n = gid / KC;
    int k = gid - n * KC;
    float x = 0.f;
    if (k < r1) x = W1[k * D_H + n];
    else if (k < r1 + r2) x = W2[(k - r1) * D_H + n];
    const int dst = ((((n >> 4) * KSE + (k >> 5)) << 6) + (((k >> 3) & 3) << 4) + (n & 15)) * 8 + (k & 7);
    WtS[dst] = (f16)x;
}

// ---- CSR build over edge_dst
__global__ void csr_hist(const int* __restrict__ edst, int* __restrict__ cnt) {
    int e = blockIdx.x * blockDim.x + threadIdx.x;
    if (e < N_EDGES) atomicAdd(&cnt[edst[e]], 1);
}

__global__ __launch_bounds__(1024) void csr_scan(const int* __restrict__ cnt,
                                                 int* __restrict__ off, int* __restrict__ pos) {
    __shared__ int sums[1024];
    const int tid = threadIdx.x;
    const int lo = tid * 98;
    const int hi = min(lo + 98, N_ATOMS);
    int s = 0;
    for (int i = lo; i < hi; ++i) s += cnt[i];
    sums[tid] = s;
    __syncthreads();
    for (int d = 1; d < 1024; d <<= 1) {
        int v = (tid >= d) ? sums[tid - d] : 0;
        __syncthreads();
        sums[tid] += v;
        __syncthreads();
    }
    int run = sums[tid] - s;  // exclusive base
    for (int i = lo; i < hi; ++i) { off[i] = run; pos[i] = run; run += cnt[i]; }
    if (tid == 1023) off[N_ATOMS] = run;
}

__global__ void csr_scatter(const int* __restrict__ edst, int* __restrict__ pos,
                            int* __restrict__ eid) {
    int e = blockIdx.x * blockDim.x + threadIdx.x;
    if (e < N_EDGES) {
        int idx = atomicAdd(&pos[edst[e]], 1);
        eid[idx] = e;
    }
}

// ---- node message sum via CSR gather.  F16M: store f16 rows.  else: block-scaled int8.
template<bool F16M>
__global__ __launch_bounds__(512) void seg_csr(
    const f16* __restrict__ H, const int* __restrict__ off, const int* __restrict__ eid,
    void* __restrict__ MnOut, float* __restrict__ Msc)
{
    const int n = blockIdx.x * 8 + (threadIdx.x >> 6);
    const int lane = threadIdx.x & 63;
    const int j0 = off[n], j1 = off[n + 1];
    float acc[8];
    #pragma unroll
    for (int k = 0; k < 8; ++k) acc[k] = 0.f;
    for (int j = j0; j < j1; ++j) {
        const int e = eid[j];
        const half8 h = *reinterpret_cast<const half8*>(&H[e * D_H + lane * 8]);
        #pragma unroll
        for (int k = 0; k < 8; ++k) acc[k] += (float)h[k];
    }
    if (F16M) {
        half8 o;
        #pragma unroll
        for (int k = 0; k < 8; ++k) o[k] = (f16)acc[k];
        *reinterpret_cast<half8*>(&((f16*)MnOut)[n * D_H + lane * 8]) = o;
    } else {
        float m = 0.f;
        #pragma unroll
        for (int k = 0; k < 8; ++k) m = fmaxf(m, fabsf(acc[k]));
        m = fmaxf(m, __shfl_xor(m, 1));
        m = fmaxf(m, __shfl_xor(m, 2));
        m = fmaxf(m, 1e-20f);
        const float s = m * (1.f / 127.f);
        const float inv_s = 127.f / m;
        if ((lane & 3) == 0) Msc[n * 16 + (lane >> 2)] = s;
        int q[8];
        #pragma unroll
        for (int k = 0; k < 8; ++k) q[k] = __float2int_rn(acc[k] * inv_s);
        uint2 o;
        o.x = (q[0] & 0xff) | ((q[1] & 0xff) << 8) | ((q[2] & 0xff) << 16) | ((unsigned)(q[3] & 0xff) << 24);
        o.y = (q[4] & 0xff) | ((q[5] & 0xff) << 8) | ((q[6] & 0xff) << 16) | ((unsigned)(q[7] & 0xff) << 24);
        *reinterpret_cast<uint2*>(&((unsigned int*)MnOut)[n * 128 + lane * 2]) = o;
    }
}

// ---- fused message-passing GEMM (in-place on Ha), BK=32, 1-deep prefetch, swizzled B
template<bool F16M>
__global__ __launch_bounds__(512) void gemm_pass(
    const float* __restrict__ V, const float* __restrict__ E,
    const int* __restrict__ esrc, const void* __restrict__ Mn,
    const float* __restrict__ Msc,
    f16* __restrict__ Ha, const f16* __restrict__ WtS, int ks_begin)
{
    __shared__ __align__(16) f16 Al[64 * LDA];
    const int tid = threadIdx.x;
    const int rowblk = blockIdx.x << 6;
    const int srow = tid >> 3;
    const int skk  = (tid & 7) << 2;
    const int e_s  = rowblk + srow;
    const int sv   = esrc[e_s];
    const int rev  = e_s ^ 1;
    const int lane = tid & 63;
    const int quad = lane >> 4;
    const int m16  = lane & 15;
    const int colbase = (tid >> 6) << 6;
    const int cb0 = (tid >> 6) << 2;          // first of this wave's 4 col-tiles
    const f16* WtL = WtS + lane * 8;          // lane-constant fragment base

    f32x4 acc[4][4];
    #pragma unroll
    for (int a = 0; a < 4; ++a)
    #pragma unroll
    for (int b = 0; b < 4; ++b)
    #pragma unroll
    for (int r = 0; r < 4; ++r) acc[a][b][r] = 0.f;

    // prefetch registers
    char4 pq; float ps; half4v pm; half4v ph; float pv[4];
    auto issue = [&](int ks) {
        const int k0 = ks << 5;
        if (k0 < D_H) {
            if (F16M) {
                pm = *reinterpret_cast<const half4v*>(&((const f16*)Mn)[sv * D_H + k0 + skk]);
            } else {
                pq = *reinterpret_cast<const char4*>(&((const char*)Mn)[sv * D_H + k0 + skk]);
                ps = Msc[sv * 16 + (k0 >> 5)];
            }
            ph = *reinterpret_cast<const half4v*>(&Ha[rev * D_H + k0 + skk]);
        } else {
            #pragma unroll
            for (int j = 0; j < 4; ++j) {
                const int kk = k0 + skk + j - D_H;
                float x = 0.f;
                if (kk < D_V) x = V[sv * D_V + kk];
                else if (kk < D_V + D_E) x = E[e_s * D_E + (kk - D_V)];
                pv[j] = x;
            }
        }
    };

    issue(ks_begin);
    for (int ks = ks_begin; ks < KSE; ++ks) {
        const int k0 = ks << 5;
        half4v w;
        if (k0 < D_H) {
            if (F16M) {
                w = pm - ph;   // packed f16 subtract
            } else {
                w[0] = (f16)((float)pq.x * ps - (float)ph[0]);
                w[1] = (f16)((float)pq.y * ps - (float)ph[1]);
                w[2] = (f16)((float)pq.z * ps - (float)ph[2]);
                w[3] = (f16)((float)pq.w * ps - (float)ph[3]);
            }
        } else {
            w[0] = (f16)pv[0]; w[1] = (f16)pv[1]; w[2] = (f16)pv[2]; w[3] = (f16)pv[3];
        }
        __syncthreads();
        *reinterpret_cast<half4v*>(&Al[srow * LDA + skk]) = w;
        __syncthreads();
        if (ks + 1 < KSE) issue(ks + 1);  // overlap with MFMA below
        half8 af[4];
        #pragma unroll
        for (int rt = 0; rt < 4; ++rt)
            af[rt] = *reinterpret_cast<const half8*>(&Al[(rt * 16 + m16) * LDA + quad * 8]);
        #pragma unroll
        for (int ct = 0; ct < 4; ++ct) {
            const half8 bf = *reinterpret_cast<const half8*>(&WtL[(((cb0 + ct) * KSE + ks) << 9)]);
            #pragma unroll
            for (int rt = 0; rt < 4; ++rt)
                acc[rt][ct] = __builtin_amdgcn_mfma_f32_16x16x32_f16(af[rt], bf, acc[rt][ct], 0, 0, 0);
        }
    }

    // epilogue: in-place overwrite is safe (all Ha[rev] reads are in-block, barrier-ordered)
    #pragma unroll
    for (int rt = 0; rt < 4; ++rt)
    #pragma unroll
    for (int ct = 0; ct < 4; ++ct)
    #pragma unroll
    for (int r = 0; r < 4; ++r) {
        const int row = rowblk + rt * 16 + quad * 4 + r;
        const int col = colbase + ct * 16 + m16;
        Ha[row * D_H + col] = (f16)fmaxf(acc[rt][ct][r], 0.f);
    }
}

// ---- output GEMM: Hv[a] = relu([M_v(512); V(133)] @ WtO + b_o), swizzled B
template<bool F16M>
__global__ __launch_bounds__(512) void gemm_out(
    const float* __restrict__ V, const void* __restrict__ Mn,
    const float* __restrict__ Msc, const float* __restrict__ bo,
    const f16* __restrict__ WtS, f16* __restrict__ Hv)
{
    __shared__ __align__(16) f16 Al[64 * LDA];
    __shared__ float bo_s[D_H];
    const int tid = threadIdx.x;
    const int rowblk = blockIdx.x << 6;
    bo_s[tid] = bo[tid];
    const int srow = tid >> 3;
    const int skk  = (tid & 7) << 2;
    const int arow = min(rowblk + srow, N_ATOMS - 1);
    const int lane = tid & 63;
    const int quad = lane >> 4;
    const int m16  = lane & 15;
    const int colbase = (tid >> 6) << 6;
    const int cb0 = (tid >> 6) << 2;
    const f16* WtL = WtS + lane * 8;

    f32x4 acc[4][4];
    #pragma unroll
    for (int a = 0; a < 4; ++a)
    #pragma unroll
    for (int b = 0; b < 4; ++b)
    #pragma unroll
    for (int r = 0; r < 4; ++r) acc[a][b][r] = 0.f;

    char4 pq; float ps; half4v pm; float pv[4];
    auto issue = [&](int ks) {
        const int k0 = ks << 5;
        if (k0 < D_H) {
            if (F16M) {
                pm = *reinterpret_cast<const half4v*>(&((const f16*)Mn)[arow * D_H + k0 + skk]);
            } else {
                pq = *reinterpret_cast<const char4*>(&((const char*)Mn)[arow * D_H + k0 + skk]);
                ps = Msc[arow * 16 + (k0 >> 5)];
            }
        } else {
            #pragma unroll
            for (int j = 0; j < 4; ++j) {
                const int kk = k0 + skk + j - D_H;
                pv[j] = (kk < D_V) ? V[arow * D_V + kk] : 0.f;
            }
        }
    };

    issue(0);
    for (int ks = 0; ks < KSE; ++ks) {
        const int k0 = ks << 5;
        half4v w;
        if (k0 < D_H) {
            if (F16M) {
                w = pm;
            } else {
                w[0] = (f16)((float)pq.x * ps);
                w[1] = (f16)((float)pq.y * ps);
                w[2] = (f16)((float)pq.z * ps);
                w[3] = (f16)((float)pq.w * ps);
            }
        } else {
            w[0] = (f16)pv[0]; w[1] = (f16)pv[1]; w[2] = (f16)pv[2]; w[3] = (f16)pv[3];
        }
        __syncthreads();
        *reinterpret_cast<half4v*>(&Al[srow * LDA + skk]) = w;
        __syncthreads();
        if (ks + 1 < KSE) issue(ks + 1);
        half8 af[4];
        #pragma unroll
        for (int rt = 0; rt < 4; ++rt)
            af[rt] = *reinterpret_cast<const half8*>(&Al[(rt * 16 + m16) * LDA + quad * 8]);
        #pragma unroll
        for (int ct = 0; ct < 4; ++ct) {
            const half8 bf = *reinterpret_cast<const half8*>(&WtL[(((cb0 + ct) * KSE + ks) << 9)]);
            #pragma unroll
            for (int rt = 0; rt < 4; ++rt)
                acc[rt][ct] = __builtin_amdgcn_mfma_f32_16x16x32_f16(af[rt], bf, acc[rt][ct], 0, 0, 0);
        }
    }

    #pragma unroll
    for (int rt = 0; rt < 4; ++rt)
    #pragma unroll
    for (int ct = 0; ct < 4; ++ct)
    #pragma unroll
    for (int r = 0; r < 4; ++r) {
        const int row = rowblk + rt * 16 + quad * 4 + r;
        if (row < N_ATOMS) {
            const int col = colbase + ct * 16 + m16;
            Hv[row * D_H + col] = (f16)fmaxf(acc[rt][ct][r] + bo_s[col], 0.f);
        }
    }
}

// ---- molecule mean: batch sorted -> contiguous atom range per mol (binary search)
__global__ __launch_bounds__(512) void mol_mean(
    const f16* __restrict__ Hv, const int* __restrict__ batch, float* __restrict__ mean)
{
    const int m = blockIdx.x;
    __shared__ int sh[2];
    if (threadIdx.x == 0) {
        int lo = 0, hi = N_ATOMS;
        while (lo < hi) { int mid = (lo + hi) >> 1; if (batch[mid] < m) lo = mid + 1; else hi = mid; }
        sh[0] = lo;
        int lo2 = lo; hi = N_ATOMS;
        while (lo2 < hi) { int mid = (lo2 + hi) >> 1; if (batch[mid] < m + 1) lo2 = mid + 1; else hi = mid; }
        sh[1] = lo2;
    }
    __syncthreads();
    const int a0 = sh[0], a1 = sh[1];
    float acc = 0.f;
    for (int a = a0; a < a1; ++a) acc += (float)Hv[(size_t)a * D_H + threadIdx.x];
    mean[m * D_H + threadIdx.x] = acc / (float)max(a1 - a0, 1);
}

__global__ __launch_bounds__(256) void bn_stats(
    const float* __restrict__ mean_in, const float* __restrict__ gamma,
    const float* __restrict__ beta, float* __restrict__ An, float* __restrict__ Bn)
{
    const int n = blockIdx.x;
    const int tid = threadIdx.x;
    float s = 0.f, s2 = 0.f;
    for (int m = tid; m < N_MOLS; m += 256) {
        float h = mean_in[m * D_H + n];
        s += h; s2 += h * h;
    }
    for (int off = 32; off > 0; off >>= 1) {
        s  += __shfl_down(s, off);
        s2 += __shfl_down(s2, off);
    }
    __shared__ float sh[8];
    const int wave = tid >> 6, lane = tid & 63;
    if (lane == 0) { sh[wave] = s; sh[4 + wave] = s2; }
    __syncthreads();
    if (tid == 0) {
        float S  = sh[0] + sh[1] + sh[2] + sh[3];
        float S2 = sh[4] + sh[5] + sh[6] + sh[7];
        float mu = S / (float)N_MOLS;
        float var = fmaxf(S2 / (float)N_MOLS - mu * mu, 0.f);
        float sc = rsqrtf(var + 1e-5f) * gamma[n];
        An[n] = sc;
        Bn[n] = beta[n] - mu * sc;
    }
}

__global__ void bn_apply(const float* __restrict__ mean_in,
                         const float* __restrict__ An, const float* __restrict__ Bn,
                         float* __restrict__ out)
{
    int gid = blockIdx.x * blockDim.x + threadIdx.x;
    int n = gid & 511;
    out[gid] = mean_in[gid] * An[n] + Bn[n];
}

extern "C" void kernel_launch(void* const* d_in, const int* in_sizes, int n_in,
                              void* d_out, int out_size, void* d_ws, size_t ws_size,
                              hipStream_t stream)
{
    (void)in_sizes; (void)n_in; (void)out_size;
    const float* V     = (const float*)d_in[0];
    const float* E     = (const float*)d_in[1];
    const int*   esrc  = (const int*)d_in[2];
    const int*   edst  = (const int*)d_in[3];
    const int*   batch = (const int*)d_in[4];
    const float* Wi    = (const float*)d_in[5];
    const float* Wh    = (const float*)d_in[6];
    const float* Wo    = (const float*)d_in[7];
    const float* bo    = (const float*)d_in[8];
    const float* gam   = (const float*)d_in[9];
    const float* bet   = (const float*)d_in[10];
    float* out = (float*)d_out;

    // workspace layout
    //  int8 mode total: 265,396,864 B.  f16 mode total: 310,196,864 B (needs ws_size >= that).
    char* ws = (char*)d_ws;
    f16*   WtC  = (f16*)(ws + 0);                   //    688,128 B (swizzled)
    f16*   WtO  = (f16*)(ws + 688128);              //    688,128 B (swizzled)
    int*   off  = (int*)(ws + 1376256);             //    400,128 B (N_ATOMS+1 ints)
    int*   eid  = (int*)(ws + 1776384);             //    800,000 B
    int*   cnt  = (int*)(ws + 2576384);             //    400,000 B (also 'pos' cursor)
    float* An   = (float*)(ws + 2992768);           //      2,048 B
    float* Bn   = (float*)(ws + 2994816);           //      2,048 B
    f16*   Ha   = (f16*)(ws + 2996864);             // 204,800,000 B (edge states; reused as Hv)
    void*  Mn   = (void*)(ws + 207796864);          // int8: 51.2 MB | f16: 102.4 MB
    float* Msc  = (float*)(ws + 258996864);         //   6,400,000 B scales (int8 mode only)
    f16*   Hv   = Ha;                                // Ha is dead after final seg_csr
    float* mean = out;                               // mol means live in d_out

    const bool f16m = ws_size >= 310196864ULL;

    // weights (swizzled to MFMA fragment order)
    wt_build_swz<<<(D_H * KC + 255) / 256, 256, 0, stream>>>(Wh, D_H, Wi, D_V + D_E, WtC);
    wt_build_swz<<<(D_H * KC + 255) / 256, 256, 0, stream>>>(Wo + D_V * D_H, D_H, Wo, D_V, WtO);

    // CSR over edge_dst (cnt doubles as scatter cursor 'pos')
    hipMemsetAsync(cnt, 0, 400000, stream);
    csr_hist<<<(N_EDGES + 511) / 512, 512, 0, stream>>>(edst, cnt);
    csr_scan<<<1, 1024, 0, stream>>>(cnt, off, cnt);
    csr_scatter<<<(N_EDGES + 511) / 512, 512, 0, stream>>>(edst, cnt, eid);

    if (f16m) {
        gemm_pass<true><<<N_EDGES / 64, 512, 0, stream>>>(V, E, esrc, Mn, Msc, Ha, WtC, 16);
        for (int it = 0; it < 2; ++it) {
            seg_csr<true><<<N_ATOMS / 8, 512, 0, stream>>>(Ha, off, eid, Mn, Msc);
            gemm_pass<true><<<N_EDGES / 64, 512, 0, stream>>>(V, E, esrc, Mn, Msc, Ha, WtC, 0);
        }
        seg_csr<true><<<N_ATOMS / 8, 512, 0, stream>>>(Ha, off, eid, Mn, Msc);
        gemm_out<true><<<(N_ATOMS + 63) / 64, 512, 0, stream>>>(V, Mn, Msc, bo, WtO, Hv);
    } else {
        gemm_pass<false><<<N_EDGES / 64, 512, 0, stream>>>(V, E, esrc, Mn, Msc, Ha, WtC, 16);
        for (int it = 0; it < 2; ++it) {
            seg_csr<false><<<N_ATOMS / 8, 512, 0, stream>>>(Ha, off, eid, Mn, Msc);
            gemm_pass<false><<<N_EDGES / 64, 512, 0, stream>>>(V, E, esrc, Mn, Msc, Ha, WtC, 0);
        }
        seg_csr<false><<<N_ATOMS / 8, 512, 0, stream>>>(Ha, off, eid, Mn, Msc);
        gemm_out<false><<<(N_ATOMS + 63) / 64, 512, 0, stream>>>(V, Mn, Msc, bo, WtO, Hv);
    }

    mol_mean<<<N_MOLS, 512, 0, stream>>>(Hv, batch, mean);
    bn_stats<<<D_H, 256, 0, stream>>>(mean, gam, bet, An, Bn);
    bn_apply<<<(N_MOLS * D_H) / 256, 256, 0, stream>>>(mean, An, Bn, out);
}